// Round 3
// baseline (129.092 us; speedup 1.0000x reference)
//
#include <hip/hip_runtime.h>
#include <hip/hip_bf16.h>
#include <stdint.h>

// AttentionHead: x[8,2048,1024](f32) @ {Wq,Wk,Wv}[1024,64](f32) + bias -> flash attn -> out[8,2048,64](f32)
// Inputs/outputs f32; internal q/k/vT scratch bf16; f32 accumulation.

typedef __attribute__((ext_vector_type(8))) short short8;   // 8 bf16 (MFMA A/B frag)
typedef __attribute__((ext_vector_type(4))) short short4v;  // 8B packed store
typedef __attribute__((ext_vector_type(4))) float floatx4;  // MFMA C/D frag / 16B f32
typedef __attribute__((ext_vector_type(2))) uint32_t uint2v;
typedef __attribute__((ext_vector_type(4))) uint32_t uint4v;

static constexpr int Tn = 2048, En = 1024, Hn = 64;
static constexpr float kLog2e = 1.44269504088896340736f;

static __device__ __forceinline__ ushort f2bf(float f) {
  uint32_t u = __builtin_bit_cast(uint32_t, f);
  u += 0x7FFFu + ((u >> 16) & 1u);          // RNE
  return (ushort)(u >> 16);
}
static __device__ __forceinline__ uint32_t cvt_pk(float lo, float hi) {
  uint32_t r;
  asm("v_cvt_pk_bf16_f32 %0, %1, %2" : "=v"(r) : "v"(lo), "v"(hi));
  return r;
}

// ---------------------------------------------------------------------------
// Kernel 0: pack Wq|Wk|Wv (f32) into bf16 B-fragment order.
// wpack[kstep][ntile][lane][8]: element = W[mat][kstep*32 + (lane>>4)*8 + j][(ntile&3)*16 + (lane&15)]
__global__ __launch_bounds__(64) void k_packw(const float* __restrict__ Wq,
                                              const float* __restrict__ Wk,
                                              const float* __restrict__ Wv,
                                              ushort* __restrict__ wpack) {
  int blk = blockIdx.x;
  int kstep = blk / 12, ntile = blk % 12;
  int l = threadIdx.x;
  const float* W = (ntile < 4) ? Wq : (ntile < 8) ? Wk : Wv;
  int col = (ntile & 3) * 16 + (l & 15);
  int k0 = kstep * 32 + (l >> 4) * 8;
  short8 v;
#pragma unroll
  for (int j = 0; j < 8; ++j) v[j] = (short)f2bf(W[(k0 + j) * Hn + col]);
  *reinterpret_cast<short8*>(wpack + ((size_t)(kstep * 12 + ntile) * 64 + l) * 8) = v;
}

// ---------------------------------------------------------------------------
// Kernel 1: QKV projection, K-split 4-way for occupancy.
// 1024 blocks x 256 thr = 4 waves; wave w handles k-quarter w of a 16-row tile.
// Partial sums merged in LDS; wave 0 does bias epilogue.
__global__ __launch_bounds__(256) void k_qkv(const float* __restrict__ x,
                                             const ushort* __restrict__ wpack,
                                             const float* __restrict__ bq,
                                             const float* __restrict__ bk,
                                             const float* __restrict__ bv,
                                             ushort* __restrict__ q,
                                             ushort* __restrict__ k,
                                             ushort* __restrict__ vT) {
  __shared__ float accS[3][64][48];    // 36.9 KB: partials from waves 1..3
  int l = threadIdx.x & 63;
  int w = threadIdx.x >> 6;            // k-quarter 0..3
  int row0 = blockIdx.x * 16;
  int lq = l & 15, g = l >> 4;
  const float* xrow = x + (size_t)(row0 + lq) * En + w * 256 + g * 8;
  const ushort* wp = wpack + (size_t)l * 8;
  floatx4 acc[12];
#pragma unroll
  for (int n = 0; n < 12; ++n) acc[n] = (floatx4){0.f, 0.f, 0.f, 0.f};

  for (int ks = 0; ks < 8; ++ks) {
    floatx4 f0 = *reinterpret_cast<const floatx4*>(xrow + ks * 32);
    floatx4 f1 = *reinterpret_cast<const floatx4*>(xrow + ks * 32 + 4);
    uint4v aw;
    aw[0] = cvt_pk(f0[0], f0[1]); aw[1] = cvt_pk(f0[2], f0[3]);
    aw[2] = cvt_pk(f1[0], f1[1]); aw[3] = cvt_pk(f1[2], f1[3]);
    short8 af = __builtin_bit_cast(short8, aw);
    int kglob = w * 8 + ks;
#pragma unroll
    for (int n = 0; n < 12; ++n) {
      short8 bf = *reinterpret_cast<const short8*>(wp + (size_t)(kglob * 12 + n) * 512);
      acc[n] = __builtin_amdgcn_mfma_f32_16x16x32_bf16(af, bf, acc[n], 0, 0, 0);
    }
  }
  if (w > 0) {
#pragma unroll
    for (int n = 0; n < 12; ++n)
      *reinterpret_cast<floatx4*>(&accS[w - 1][l][n * 4]) = acc[n];
  }
  __syncthreads();
  if (w == 0) {
#pragma unroll
    for (int n = 0; n < 12; ++n)
#pragma unroll
      for (int si = 0; si < 3; ++si)
        acc[n] += *reinterpret_cast<const floatx4*>(&accS[si][l][n * 4]);
    // epilogue: C/D frag col = lane&15, row = (lane>>4)*4 + r
    int b = row0 >> 11;
    int tloc0 = (row0 & (Tn - 1)) + g * 4;
#pragma unroll
    for (int n = 0; n < 12; ++n) {
      int mat = n >> 2;
      int h = (n & 3) * 16 + lq;
      const float* bias = (mat == 0) ? bq : (mat == 1) ? bk : bv;
      float bias_f = bias[h];
      if (mat < 2) {
        ushort* dst = (mat == 0) ? q : k;
#pragma unroll
        for (int r = 0; r < 4; ++r)
          dst[(size_t)(row0 + g * 4 + r) * Hn + h] = f2bf(acc[n][r] + bias_f);
      } else {
        uint2v pk;
        pk[0] = cvt_pk(acc[n][0] + bias_f, acc[n][1] + bias_f);
        pk[1] = cvt_pk(acc[n][2] + bias_f, acc[n][3] + bias_f);
        *reinterpret_cast<uint2v*>(vT + ((size_t)b * Hn + h) * Tn + tloc0) = pk;
      }
    }
  }
}

// ---------------------------------------------------------------------------
// Kernel 2: flash attention, transposed orientation, barrier-free main loop.
//  S^T = mfma(A=K, B=Q^T): lane holds q=lane&15 (col), kv=(lane>>4)*4+r (row) -> softmax row in-lane.
//  out^T = mfma(A=V^T, B=P^T): col=q=lane&15 -> m/l/rescale in-lane.
// 512 blocks x 512 thr: 8 waves = 2 q-tiles x 4-way KV split (merged via LDS at end).
__global__ __launch_bounds__(512) void k_attn(const ushort* __restrict__ qm,
                                              const ushort* __restrict__ km,
                                              const ushort* __restrict__ vT,
                                              const int* __restrict__ mask,
                                              float* __restrict__ out) {
  __shared__ ushort P[8][16 * 72];        // per-wave P[q][kv] (no cross-wave sharing!)
  __shared__ float accS[2][3][64][20];    // [qt][split-1][lane][16 + pad]
  __shared__ float mS[2][3][64], lS[2][3][64];

  int tid = threadIdx.x;
  int l = tid & 63, w = tid >> 6;         // wave 0..7
  int qt = w >> 2, s = w & 3;             // q-tile, kv-split
  int bid = blockIdx.x;
  int b = bid >> 6;                       // 64 blocks per batch (32 q rows each)
  int q0 = (bid & 63) * 32 + qt * 16;
  int lq = l & 15, g = l >> 4;

  const ushort* qbase = qm + ((size_t)(b * Tn + q0 + lq)) * Hn + g * 8;
  short8 qf0 = *reinterpret_cast<const short8*>(qbase);
  short8 qf1 = *reinterpret_cast<const short8*>(qbase + 32);

  const ushort* kbase = km + ((size_t)(b * Tn) + lq) * Hn + g * 8;
  const ushort* vbase = vT + ((size_t)b * Hn + lq) * Tn + g * 8;
  const int* mbase = mask + b * Tn + l;
  ushort* Pw = &P[w][0];
  uint32_t* Pw32 = reinterpret_cast<uint32_t*>(Pw);

  float m = -1e30f, lsum = 0.f;
  floatx4 acc[4];
#pragma unroll
  for (int mt = 0; mt < 4; ++mt) acc[mt] = (floatx4){0.f, 0.f, 0.f, 0.f};

  for (int it = 0; it < 8; ++it) {
    const int kv0 = s * 512 + it * 64;
    // ---- QK^T (S^T) ----
    floatx4 st[4];
#pragma unroll
    for (int t = 0; t < 4; ++t) {
      const ushort* kp = kbase + (size_t)(kv0 + t * 16) * Hn;
      short8 kf0 = *reinterpret_cast<const short8*>(kp);
      short8 kf1 = *reinterpret_cast<const short8*>(kp + 32);
      floatx4 z = (floatx4){0.f, 0.f, 0.f, 0.f};
      z = __builtin_amdgcn_mfma_f32_16x16x32_bf16(kf0, qf0, z, 0, 0, 0);
      z = __builtin_amdgcn_mfma_f32_16x16x32_bf16(kf1, qf1, z, 0, 0, 0);
      st[t] = z;
    }
    // ---- mask + online softmax (row in-lane: 16 values + 2 shuffles) ----
    unsigned long long bal = __ballot(mbase[kv0] != 0);
    float sc[4][4];
    float tmax = -1e30f;
#pragma unroll
    for (int t = 0; t < 4; ++t)
#pragma unroll
      for (int r = 0; r < 4; ++r) {
        float sv = st[t][r] * 0.125f;
        int kvloc = t * 16 + g * 4 + r;
        if (!((bal >> kvloc) & 1ull)) sv = -1e9f;
        sc[t][r] = sv;
        tmax = fmaxf(tmax, sv);
      }
    tmax = fmaxf(tmax, __shfl_xor(tmax, 16));
    tmax = fmaxf(tmax, __shfl_xor(tmax, 32));
    // defer-max (T13): skip rescale when the running max doesn't grow by >8
    if (!__all(tmax - m <= 8.0f)) {
      float mnew = fmaxf(m, tmax);
      float alpha = exp2f((m - mnew) * kLog2e);
      lsum *= alpha;
#pragma unroll
      for (int mt = 0; mt < 4; ++mt) acc[mt] *= alpha;
      m = mnew;
    }
    float ts = 0.f;
#pragma unroll
    for (int t = 0; t < 4; ++t) {
      float p0 = exp2f((sc[t][0] - m) * kLog2e);
      float p1 = exp2f((sc[t][1] - m) * kLog2e);
      float p2 = exp2f((sc[t][2] - m) * kLog2e);
      float p3 = exp2f((sc[t][3] - m) * kLog2e);
      ts += (p0 + p1) + (p2 + p3);
      uint2v pw;
      pw[0] = cvt_pk(p0, p1);
      pw[1] = cvt_pk(p2, p3);
      *reinterpret_cast<uint2v*>(Pw32 + (lq * 36 + t * 8 + g * 2)) = pw;
    }
    ts += __shfl_xor(ts, 16);
    ts += __shfl_xor(ts, 32);
    lsum += ts;
    // ---- PV (out^T += V^T @ P^T) ---- (within-wave LDS dependency only; no barrier)
    short8 pf0 = *reinterpret_cast<const short8*>(Pw + lq * 72 + g * 8);
    short8 pf1 = *reinterpret_cast<const short8*>(Pw + lq * 72 + 32 + g * 8);
#pragma unroll
    for (int mt = 0; mt < 4; ++mt) {
      const ushort* vp = vbase + (size_t)mt * 16 * Tn + kv0;
      short8 vf0 = *reinterpret_cast<const short8*>(vp);
      short8 vf1 = *reinterpret_cast<const short8*>(vp + 32);
      acc[mt] = __builtin_amdgcn_mfma_f32_16x16x32_bf16(vf0, pf0, acc[mt], 0, 0, 0);
      acc[mt] = __builtin_amdgcn_mfma_f32_16x16x32_bf16(vf1, pf1, acc[mt], 0, 0, 0);
    }
  }

  // ---- merge the 4 KV splits (waves qt*?+s share q-tile qt) ----
  if (s > 0) {
#pragma unroll
    for (int mt = 0; mt < 4; ++mt)
      *reinterpret_cast<floatx4*>(&accS[qt][s - 1][l][mt * 4]) = acc[mt];
    mS[qt][s - 1][l] = m;
    lS[qt][s - 1][l] = lsum;
  }
  __syncthreads();
  if (s == 0) {
    float mtot = m;
#pragma unroll
    for (int si = 0; si < 3; ++si) mtot = fmaxf(mtot, mS[qt][si][l]);
    float e0 = exp2f((m - mtot) * kLog2e);
    float ltot = lsum * e0;
    float res[4][4];
#pragma unroll
    for (int mt = 0; mt < 4; ++mt)
#pragma unroll
      for (int r = 0; r < 4; ++r) res[mt][r] = acc[mt][r] * e0;
#pragma unroll
    for (int si = 0; si < 3; ++si) {
      float e = exp2f((mS[qt][si][l] - mtot) * kLog2e);
      ltot += lS[qt][si][l] * e;
#pragma unroll
      for (int mt = 0; mt < 4; ++mt) {
        floatx4 a = *reinterpret_cast<const floatx4*>(&accS[qt][si][l][mt * 4]);
#pragma unroll
        for (int r = 0; r < 4; ++r) res[mt][r] += a[r] * e;
      }
    }
    float inv = 1.0f / ltot;
    float* obase = out + ((size_t)(b * Tn + q0 + lq)) * Hn;
#pragma unroll
    for (int mt = 0; mt < 4; ++mt) {
      floatx4 o;
#pragma unroll
      for (int r = 0; r < 4; ++r) o[r] = res[mt][r] * inv;
      *reinterpret_cast<floatx4*>(obase + mt * 16 + g * 4) = o;
    }
  }
}

// ---------------------------------------------------------------------------
extern "C" void kernel_launch(void* const* d_in, const int* in_sizes, int n_in,
                              void* d_out, int out_size, void* d_ws, size_t ws_size,
                              hipStream_t stream) {
  const float* x  = (const float*)d_in[0];
  const float* Wq = (const float*)d_in[1];
  const float* bq = (const float*)d_in[2];
  const float* Wk = (const float*)d_in[3];
  const float* bk = (const float*)d_in[4];
  const float* Wv = (const float*)d_in[5];
  const float* bv = (const float*)d_in[6];
  const int* mask = (const int*)d_in[7];
  float* outp = (float*)d_out;

  ushort* wpack = (ushort*)d_ws;                       // 384 KB
  ushort* qbuf  = wpack + 196608;                      // 2 MB bf16
  ushort* kbuf  = qbuf + (size_t)16384 * 64;           // 2 MB
  ushort* vTbuf = kbuf + (size_t)16384 * 64;           // [8][64][2048] bf16, 2 MB

  hipLaunchKernelGGL(k_packw, dim3(384), dim3(64), 0, stream, Wq, Wk, Wv, wpack);
  hipLaunchKernelGGL(k_qkv, dim3(1024), dim3(256), 0, stream, x, wpack, bq, bk, bv,
                     qbuf, kbuf, vTbuf);
  hipLaunchKernelGGL(k_attn, dim3(512), dim3(512), 0, stream, qbuf, kbuf, vTbuf, mask, outp);
}

// Round 4
// 98.581 us; speedup vs baseline: 1.3095x; 1.3095x over previous
//
#include <hip/hip_runtime.h>
#include <hip/hip_bf16.h>
#include <stdint.h>

// AttentionHead: x[8,2048,1024](f32) @ {Wq,Wk,Wv}[1024,64](f32) + bias -> flash attn -> out[8,2048,64](f32)
// f32 I/O; internal q/k/vT scratch bf16; f32 accumulation.

typedef __attribute__((ext_vector_type(8))) short short8;   // 8 bf16 (MFMA A/B frag)
typedef __attribute__((ext_vector_type(4))) float floatx4;  // MFMA C/D frag / 16B f32
typedef __attribute__((ext_vector_type(2))) uint32_t uint2v;
typedef __attribute__((ext_vector_type(4))) uint32_t uint4v;

static constexpr int Tn = 2048, En = 1024, Hn = 64;
static constexpr float kLog2e = 1.44269504088896340736f;

static __device__ __forceinline__ ushort f2bf(float f) {
  uint32_t u = __builtin_bit_cast(uint32_t, f);
  u += 0x7FFFu + ((u >> 16) & 1u);          // RNE
  return (ushort)(u >> 16);
}
static __device__ __forceinline__ uint32_t cvt_pk(float lo, float hi) {
  uint32_t r;
  asm("v_cvt_pk_bf16_f32 %0, %1, %2" : "=v"(r) : "v"(lo), "v"(hi));
  return r;
}

// ---------------------------------------------------------------------------
// Kernel 0: pack Wq|Wk|Wv (f32) into bf16 B-fragment order.
// wpack[kstep][ntile][lane][8]: element = W[mat][kstep*32 + (lane>>4)*8 + j][(ntile&3)*16 + (lane&15)]
__global__ __launch_bounds__(64) void k_packw(const float* __restrict__ Wq,
                                              const float* __restrict__ Wk,
                                              const float* __restrict__ Wv,
                                              ushort* __restrict__ wpack) {
  int blk = blockIdx.x;
  int kstep = blk / 12, ntile = blk % 12;
  int l = threadIdx.x;
  const float* W = (ntile < 4) ? Wq : (ntile < 8) ? Wk : Wv;
  int col = (ntile & 3) * 16 + (l & 15);
  int k0 = kstep * 32 + (l >> 4) * 8;
  short8 v;
#pragma unroll
  for (int j = 0; j < 8; ++j) v[j] = (short)f2bf(W[(k0 + j) * Hn + col]);
  *reinterpret_cast<short8*>(wpack + ((size_t)(kstep * 12 + ntile) * 64 + l) * 8) = v;
}

// ---------------------------------------------------------------------------
// Kernel 1: QKV projection. n-split x2, K-split x2: 1024 blocks x 4 waves.
// wave (ns, ks2): 6 n-tiles (n0=ns*6), K-half ks2. Both operands double-buffered
// in registers (prefetch iteration i+1 while computing i). Pair-merge via LDS.
__global__ __launch_bounds__(256, 4) void k_qkv(const float* __restrict__ x,
                                                const ushort* __restrict__ wpack,
                                                const float* __restrict__ bq,
                                                const float* __restrict__ bk,
                                                const float* __restrict__ bv,
                                                ushort* __restrict__ q,
                                                ushort* __restrict__ k,
                                                ushort* __restrict__ vT) {
  __shared__ float accS[2][64][28];     // 14.3 KB: ks2=1 partials per ns
  int l = threadIdx.x & 63;
  int w = threadIdx.x >> 6;
  int ns = w & 1, ks2 = w >> 1;
  int n0 = ns * 6;
  int row0 = blockIdx.x * 16;
  int lq = l & 15, g = l >> 4;
  const float* xrow = x + (size_t)(row0 + lq) * En + ks2 * 512 + g * 8;
  const ushort* wp = wpack + (size_t)l * 8;

  floatx4 acc[6];
#pragma unroll
  for (int n = 0; n < 6; ++n) acc[n] = (floatx4){0.f, 0.f, 0.f, 0.f};

  // prologue: prefetch i=0 operands
  floatx4 xa[2][2];
  short8 bfr[2][6];
  xa[0][0] = *reinterpret_cast<const floatx4*>(xrow);
  xa[0][1] = *reinterpret_cast<const floatx4*>(xrow + 4);
  {
    int ks = ks2 * 16;
#pragma unroll
    for (int nn = 0; nn < 6; ++nn)
      bfr[0][nn] = *reinterpret_cast<const short8*>(wp + (size_t)(ks * 12 + n0 + nn) * 512);
  }

#pragma unroll
  for (int i = 0; i < 16; ++i) {
    const int cur = i & 1, nxt = cur ^ 1;
    if (i < 15) {                       // prefetch i+1 (consumed next iter)
      xa[nxt][0] = *reinterpret_cast<const floatx4*>(xrow + (i + 1) * 32);
      xa[nxt][1] = *reinterpret_cast<const floatx4*>(xrow + (i + 1) * 32 + 4);
      int ksn = ks2 * 16 + i + 1;
#pragma unroll
      for (int nn = 0; nn < 6; ++nn)
        bfr[nxt][nn] = *reinterpret_cast<const short8*>(wp + (size_t)(ksn * 12 + n0 + nn) * 512);
    }
    uint4v aw;
    aw[0] = cvt_pk(xa[cur][0][0], xa[cur][0][1]);
    aw[1] = cvt_pk(xa[cur][0][2], xa[cur][0][3]);
    aw[2] = cvt_pk(xa[cur][1][0], xa[cur][1][1]);
    aw[3] = cvt_pk(xa[cur][1][2], xa[cur][1][3]);
    short8 af = __builtin_bit_cast(short8, aw);
#pragma unroll
    for (int nn = 0; nn < 6; ++nn)
      acc[nn] = __builtin_amdgcn_mfma_f32_16x16x32_bf16(af, bfr[cur][nn], acc[nn], 0, 0, 0);
  }

  if (ks2 == 1) {
#pragma unroll
    for (int nn = 0; nn < 6; ++nn)
      *reinterpret_cast<floatx4*>(&accS[ns][l][nn * 4]) = acc[nn];
  }
  __syncthreads();
  if (ks2 == 0) {
#pragma unroll
    for (int nn = 0; nn < 6; ++nn)
      acc[nn] += *reinterpret_cast<const floatx4*>(&accS[ns][l][nn * 4]);
    // epilogue: C/D frag col = lane&15, row = (lane>>4)*4 + r
    int b = row0 >> 11;
    int tloc0 = (row0 & (Tn - 1)) + g * 4;
#pragma unroll
    for (int nn = 0; nn < 6; ++nn) {
      int n = n0 + nn;
      int mat = n >> 2;
      int h = (n & 3) * 16 + lq;
      const float* bias = (mat == 0) ? bq : (mat == 1) ? bk : bv;
      float bias_f = bias[h];
      if (mat < 2) {
        ushort* dst = (mat == 0) ? q : k;
#pragma unroll
        for (int r = 0; r < 4; ++r)
          dst[(size_t)(row0 + g * 4 + r) * Hn + h] = f2bf(acc[nn][r] + bias_f);
      } else {
        uint2v pk;
        pk[0] = cvt_pk(acc[nn][0] + bias_f, acc[nn][1] + bias_f);
        pk[1] = cvt_pk(acc[nn][2] + bias_f, acc[nn][3] + bias_f);
        *reinterpret_cast<uint2v*>(vT + ((size_t)b * Hn + h) * Tn + tloc0) = pk;
      }
    }
  }
}

// ---------------------------------------------------------------------------
// Kernel 2: flash attention, transposed orientation, KVBLK=32, 16 iters.
// K frags double-buffered (prefetch it+1); V issued at iter top, consumed after
// softmax (~300cy cover); mask pre-folded into 8 ballots (no in-loop loads).
// 512 blocks x 512 thr: 8 waves = 2 q-tiles x 4-way KV split, merged via LDS.
__global__ __launch_bounds__(512, 4) void k_attn(const ushort* __restrict__ qm,
                                                 const ushort* __restrict__ km,
                                                 const ushort* __restrict__ vT,
                                                 const int* __restrict__ mask,
                                                 float* __restrict__ out) {
  __shared__ ushort P[8][16 * 40];        // per-wave P[q 16][kv 32], pad 32->40
  __shared__ float accS[2][3][64][20];    // [qt][split-1][lane][16+pad]
  __shared__ float mS[2][3][64], lS[2][3][64];

  int tid = threadIdx.x;
  int l = tid & 63, w = tid >> 6;
  int qt = w >> 2, s = w & 3;             // q-tile, kv-split
  int bid = blockIdx.x;
  int b = bid >> 6;
  int q0 = (bid & 63) * 32 + qt * 16;
  int lq = l & 15, g = l >> 4;

  const ushort* qbase = qm + ((size_t)(b * Tn + q0 + lq)) * Hn + g * 8;
  short8 qf0 = *reinterpret_cast<const short8*>(qbase);
  short8 qf1 = *reinterpret_cast<const short8*>(qbase + 32);

  const ushort* kbase = km + ((size_t)(b * Tn + s * 512) + lq) * Hn + g * 8;
  const ushort* vbase = vT + ((size_t)b * Hn + lq) * Tn + s * 512 + g * 8;
  ushort* Pw = &P[w][0];
  uint32_t* Pw32 = reinterpret_cast<uint32_t*>(Pw);

  // mask -> 8 precomputed 64-key ballots (keys s*512 + j*64 + lane)
  const int* mrow = mask + b * Tn + s * 512 + l;
  unsigned long long bal64[8];
#pragma unroll
  for (int j = 0; j < 8; ++j) bal64[j] = __ballot(mrow[j * 64] != 0);

  float m = -1e30f, lsum = 0.f;
  floatx4 acc[4];
#pragma unroll
  for (int mt = 0; mt < 4; ++mt) acc[mt] = (floatx4){0.f, 0.f, 0.f, 0.f};

  short8 kf[2][4];
#pragma unroll
  for (int t = 0; t < 2; ++t)
#pragma unroll
    for (int h = 0; h < 2; ++h)
      kf[0][t * 2 + h] = *reinterpret_cast<const short8*>(kbase + (size_t)(t * 16) * Hn + h * 32);

#pragma unroll
  for (int it = 0; it < 16; ++it) {
    const int cur = it & 1, nxt = cur ^ 1;
    if (it < 15) {                        // prefetch next K tile
      const ushort* kp = kbase + (size_t)((it + 1) * 32) * Hn;
#pragma unroll
      for (int t = 0; t < 2; ++t)
#pragma unroll
        for (int h = 0; h < 2; ++h)
          kf[nxt][t * 2 + h] = *reinterpret_cast<const short8*>(kp + (size_t)(t * 16) * Hn + h * 32);
    }
    short8 vf[4];                         // V for this iter; consumed after softmax
#pragma unroll
    for (int mt = 0; mt < 4; ++mt)
      vf[mt] = *reinterpret_cast<const short8*>(vbase + (size_t)mt * 16 * Tn + it * 32);

    // ---- QK^T (S^T): lane holds q=lq (col), kv = t*16 + g*4 + r ----
    floatx4 st[2];
#pragma unroll
    for (int t = 0; t < 2; ++t) {
      floatx4 z = (floatx4){0.f, 0.f, 0.f, 0.f};
      z = __builtin_amdgcn_mfma_f32_16x16x32_bf16(kf[cur][t * 2 + 0], qf0, z, 0, 0, 0);
      z = __builtin_amdgcn_mfma_f32_16x16x32_bf16(kf[cur][t * 2 + 1], qf1, z, 0, 0, 0);
      st[t] = z;
    }
    // ---- mask + online softmax (8 scores in-lane + 2 shuffles) ----
    unsigned int bal32 = (unsigned int)(bal64[it >> 1] >> ((it & 1) * 32));
    float sc[2][4];
    float tmax = -1e30f;
#pragma unroll
    for (int t = 0; t < 2; ++t)
#pragma unroll
      for (int r = 0; r < 4; ++r) {
        float sv = st[t][r] * 0.125f;
        int kvloc = t * 16 + g * 4 + r;
        if (!((bal32 >> kvloc) & 1u)) sv = -1e9f;
        sc[t][r] = sv;
        tmax = fmaxf(tmax, sv);
      }
    tmax = fmaxf(tmax, __shfl_xor(tmax, 16));
    tmax = fmaxf(tmax, __shfl_xor(tmax, 32));
    if (!__all(tmax - m <= 8.0f)) {       // defer-max (T13)
      float mnew = fmaxf(m, tmax);
      float alpha = exp2f((m - mnew) * kLog2e);
      lsum *= alpha;
#pragma unroll
      for (int mt = 0; mt < 4; ++mt) acc[mt] *= alpha;
      m = mnew;
    }
    float ts = 0.f;
#pragma unroll
    for (int t = 0; t < 2; ++t) {
      float p0 = exp2f((sc[t][0] - m) * kLog2e);
      float p1 = exp2f((sc[t][1] - m) * kLog2e);
      float p2 = exp2f((sc[t][2] - m) * kLog2e);
      float p3 = exp2f((sc[t][3] - m) * kLog2e);
      ts += (p0 + p1) + (p2 + p3);
      uint2v pw;
      pw[0] = cvt_pk(p0, p1);
      pw[1] = cvt_pk(p2, p3);
      *reinterpret_cast<uint2v*>(Pw32 + (lq * 20 + t * 8 + g * 2)) = pw;
    }
    ts += __shfl_xor(ts, 16);
    ts += __shfl_xor(ts, 32);
    lsum += ts;
    // ---- PV: out^T += V^T @ P^T (within-wave LDS dep only) ----
    short8 pf = *reinterpret_cast<const short8*>(Pw + lq * 40 + g * 8);
#pragma unroll
    for (int mt = 0; mt < 4; ++mt)
      acc[mt] = __builtin_amdgcn_mfma_f32_16x16x32_bf16(vf[mt], pf, acc[mt], 0, 0, 0);
  }

  // ---- merge the 4 KV splits ----
  if (s > 0) {
#pragma unroll
    for (int mt = 0; mt < 4; ++mt)
      *reinterpret_cast<floatx4*>(&accS[qt][s - 1][l][mt * 4]) = acc[mt];
    mS[qt][s - 1][l] = m;
    lS[qt][s - 1][l] = lsum;
  }
  __syncthreads();
  if (s == 0) {
    float mtot = m;
#pragma unroll
    for (int si = 0; si < 3; ++si) mtot = fmaxf(mtot, mS[qt][si][l]);
    float e0 = exp2f((m - mtot) * kLog2e);
    float ltot = lsum * e0;
    float res[4][4];
#pragma unroll
    for (int mt = 0; mt < 4; ++mt)
#pragma unroll
      for (int r = 0; r < 4; ++r) res[mt][r] = acc[mt][r] * e0;
#pragma unroll
    for (int si = 0; si < 3; ++si) {
      float e = exp2f((mS[qt][si][l] - mtot) * kLog2e);
      ltot += lS[qt][si][l] * e;
#pragma unroll
      for (int mt = 0; mt < 4; ++mt) {
        floatx4 a = *reinterpret_cast<const floatx4*>(&accS[qt][si][l][mt * 4]);
#pragma unroll
        for (int r = 0; r < 4; ++r) res[mt][r] += a[r] * e;
      }
    }
    float inv = 1.0f / ltot;
    float* obase = out + ((size_t)(b * Tn + q0 + lq)) * Hn;
#pragma unroll
    for (int mt = 0; mt < 4; ++mt) {
      floatx4 o;
#pragma unroll
      for (int r = 0; r < 4; ++r) o[r] = res[mt][r] * inv;
      *reinterpret_cast<floatx4*>(obase + mt * 16 + g * 4) = o;
    }
  }
}

// ---------------------------------------------------------------------------
extern "C" void kernel_launch(void* const* d_in, const int* in_sizes, int n_in,
                              void* d_out, int out_size, void* d_ws, size_t ws_size,
                              hipStream_t stream) {
  const float* x  = (const float*)d_in[0];
  const float* Wq = (const float*)d_in[1];
  const float* bq = (const float*)d_in[2];
  const float* Wk = (const float*)d_in[3];
  const float* bk = (const float*)d_in[4];
  const float* Wv = (const float*)d_in[5];
  const float* bv = (const float*)d_in[6];
  const int* mask = (const int*)d_in[7];
  float* outp = (float*)d_out;

  ushort* wpack = (ushort*)d_ws;                       // 384 KB
  ushort* qbuf  = wpack + 196608;                      // 2 MB bf16
  ushort* kbuf  = qbuf + (size_t)16384 * 64;           // 2 MB
  ushort* vTbuf = kbuf + (size_t)16384 * 64;           // [8][64][2048] bf16, 2 MB

  hipLaunchKernelGGL(k_packw, dim3(384), dim3(64), 0, stream, Wq, Wk, Wv, wpack);
  hipLaunchKernelGGL(k_qkv, dim3(1024), dim3(256), 0, stream, x, wpack, bq, bk, bv,
                     qbuf, kbuf, vTbuf);
  hipLaunchKernelGGL(k_attn, dim3(512), dim3(512), 0, stream, qbuf, kbuf, vTbuf, mask, outp);
}

// Round 5
// 85.391 us; speedup vs baseline: 1.5118x; 1.1545x over previous
//
#include <hip/hip_runtime.h>
#include <hip/hip_bf16.h>
#include <stdint.h>

// AttentionHead: x[8,2048,1024](f32) @ {Wq,Wk,Wv}[1024,64](f32) + bias -> flash attn -> out[8,2048,64](f32)
// f32 I/O; internal q/k/vT scratch bf16 (q pre-scaled by 1/8); f32 accumulation.

typedef __attribute__((ext_vector_type(8))) short short8;   // 8 bf16 (MFMA A/B frag)
typedef __attribute__((ext_vector_type(4))) float floatx4;  // MFMA C/D frag / 16B f32
typedef __attribute__((ext_vector_type(2))) uint32_t uint2v;
typedef __attribute__((ext_vector_type(4))) uint32_t uint4v;

static constexpr int Tn = 2048, En = 1024, Hn = 64;
static constexpr float kLog2e = 1.44269504088896340736f;

static __device__ __forceinline__ ushort f2bf(float f) {
  uint32_t u = __builtin_bit_cast(uint32_t, f);
  u += 0x7FFFu + ((u >> 16) & 1u);          // RNE
  return (ushort)(u >> 16);
}
static __device__ __forceinline__ uint32_t cvt_pk(float lo, float hi) {
  uint32_t r;
  asm("v_cvt_pk_bf16_f32 %0, %1, %2" : "=v"(r) : "v"(lo), "v"(hi));
  return r;
}

// ---------------------------------------------------------------------------
// Kernel 0: pack Wq|Wk|Wv (f32) into bf16 B-fragment order.
__global__ __launch_bounds__(64) void k_packw(const float* __restrict__ Wq,
                                              const float* __restrict__ Wk,
                                              const float* __restrict__ Wv,
                                              ushort* __restrict__ wpack) {
  int blk = blockIdx.x;
  int kstep = blk / 12, ntile = blk % 12;
  int l = threadIdx.x;
  const float* W = (ntile < 4) ? Wq : (ntile < 8) ? Wk : Wv;
  int col = (ntile & 3) * 16 + (l & 15);
  int k0 = kstep * 32 + (l >> 4) * 8;
  short8 v;
#pragma unroll
  for (int j = 0; j < 8; ++j) v[j] = (short)f2bf(W[(k0 + j) * Hn + col]);
  *reinterpret_cast<short8*>(wpack + ((size_t)(kstep * 12 + ntile) * 64 + l) * 8) = v;
}

// ---------------------------------------------------------------------------
// Kernel 1: QKV projection (round-4 structure). q stored pre-scaled by 1/8;
// v stored in tiled layout vT2[b][tile=64][h=64][kv=32].
__global__ __launch_bounds__(256, 4) void k_qkv(const float* __restrict__ x,
                                                const ushort* __restrict__ wpack,
                                                const float* __restrict__ bq,
                                                const float* __restrict__ bk,
                                                const float* __restrict__ bv,
                                                ushort* __restrict__ q,
                                                ushort* __restrict__ k,
                                                ushort* __restrict__ vT2) {
  __shared__ float accS[2][64][28];
  int l = threadIdx.x & 63;
  int w = threadIdx.x >> 6;
  int ns = w & 1, ks2 = w >> 1;
  int n0 = ns * 6;
  int row0 = blockIdx.x * 16;
  int lq = l & 15, g = l >> 4;
  const float* xrow = x + (size_t)(row0 + lq) * En + ks2 * 512 + g * 8;
  const ushort* wp = wpack + (size_t)l * 8;

  floatx4 acc[6];
#pragma unroll
  for (int n = 0; n < 6; ++n) acc[n] = (floatx4){0.f, 0.f, 0.f, 0.f};

  floatx4 xa[2][2];
  short8 bfr[2][6];
  xa[0][0] = *reinterpret_cast<const floatx4*>(xrow);
  xa[0][1] = *reinterpret_cast<const floatx4*>(xrow + 4);
  {
    int ks = ks2 * 16;
#pragma unroll
    for (int nn = 0; nn < 6; ++nn)
      bfr[0][nn] = *reinterpret_cast<const short8*>(wp + (size_t)(ks * 12 + n0 + nn) * 512);
  }

#pragma unroll
  for (int i = 0; i < 16; ++i) {
    const int cur = i & 1, nxt = cur ^ 1;
    if (i < 15) {
      xa[nxt][0] = *reinterpret_cast<const floatx4*>(xrow + (i + 1) * 32);
      xa[nxt][1] = *reinterpret_cast<const floatx4*>(xrow + (i + 1) * 32 + 4);
      int ksn = ks2 * 16 + i + 1;
#pragma unroll
      for (int nn = 0; nn < 6; ++nn)
        bfr[nxt][nn] = *reinterpret_cast<const short8*>(wp + (size_t)(ksn * 12 + n0 + nn) * 512);
    }
    uint4v aw;
    aw[0] = cvt_pk(xa[cur][0][0], xa[cur][0][1]);
    aw[1] = cvt_pk(xa[cur][0][2], xa[cur][0][3]);
    aw[2] = cvt_pk(xa[cur][1][0], xa[cur][1][1]);
    aw[3] = cvt_pk(xa[cur][1][2], xa[cur][1][3]);
    short8 af = __builtin_bit_cast(short8, aw);
#pragma unroll
    for (int nn = 0; nn < 6; ++nn)
      acc[nn] = __builtin_amdgcn_mfma_f32_16x16x32_bf16(af, bfr[cur][nn], acc[nn], 0, 0, 0);
  }

  if (ks2 == 1) {
#pragma unroll
    for (int nn = 0; nn < 6; ++nn)
      *reinterpret_cast<floatx4*>(&accS[ns][l][nn * 4]) = acc[nn];
  }
  __syncthreads();
  if (ks2 == 0) {
#pragma unroll
    for (int nn = 0; nn < 6; ++nn)
      acc[nn] += *reinterpret_cast<const floatx4*>(&accS[ns][l][nn * 4]);
    int b = row0 >> 11;
#pragma unroll
    for (int nn = 0; nn < 6; ++nn) {
      int n = n0 + nn;
      int mat = n >> 2;
      int h = (n & 3) * 16 + lq;
      const float* bias = (mat == 0) ? bq : (mat == 1) ? bk : bv;
      float bias_f = bias[h];
      if (mat == 0) {          // q: pre-scale by 1/8 (softmax scale folded in)
#pragma unroll
        for (int r = 0; r < 4; ++r)
          q[(size_t)(row0 + g * 4 + r) * Hn + h] = f2bf((acc[nn][r] + bias_f) * 0.125f);
      } else if (mat == 1) {
#pragma unroll
        for (int r = 0; r < 4; ++r)
          k[(size_t)(row0 + g * 4 + r) * Hn + h] = f2bf(acc[nn][r] + bias_f);
      } else {                 // v -> vT2[b][tile][h][32]
        int tile = (row0 & (Tn - 1)) >> 5;
        int off = (row0 & 16) + g * 4;
        uint2v pk;
        pk[0] = cvt_pk(acc[nn][0] + bias_f, acc[nn][1] + bias_f);
        pk[1] = cvt_pk(acc[nn][2] + bias_f, acc[nn][3] + bias_f);
        *reinterpret_cast<uint2v*>(vT2 + (((size_t)b * 64 + tile) * 64 + h) * 32 + off) = pk;
      }
    }
  }
}

// ---------------------------------------------------------------------------
// Kernel 2: flash attention, VALU-lean. KVBLK=32, 16 iters, zero in-loop
// shuffles/barriers. 512 blocks x 512 thr: 8 waves = 2 qt x 4-way KV split.
__global__ __launch_bounds__(512, 4) void k_attn(const ushort* __restrict__ qm,
                                                 const ushort* __restrict__ km,
                                                 const ushort* __restrict__ vT2,
                                                 const int* __restrict__ mask,
                                                 float* __restrict__ out) {
  __shared__ union SMem {
    ushort P[8][16 * 40];                          // in-loop per-wave P (10.2 KB)
    struct {
      float accS[2][3][64][20];                    // merge phase (33.8 KB)
      float mS[2][3][64];
      float lS[2][3][64];
    } mg;
  } sm;

  int tid = threadIdx.x;
  int l = tid & 63, w = tid >> 6;
  int qt = w >> 2, s = w & 3;
  int bid = blockIdx.x;
  int b = bid >> 6;
  int q0 = (bid & 63) * 32 + qt * 16;
  int lq = l & 15, g = l >> 4;

  const ushort* qbase = qm + ((size_t)(b * Tn + q0 + lq)) * Hn + g * 8;
  short8 qf0 = *reinterpret_cast<const short8*>(qbase);
  short8 qf1 = *reinterpret_cast<const short8*>(qbase + 32);

  const ushort* kp = km + ((size_t)(b * Tn + s * 512) + lq) * Hn + g * 8;      // + it*2048 + t*1024 + h*32
  const ushort* vp = vT2 + (((size_t)b * 64 + s * 16) * 64 + lq) * 32 + g * 8; // + it*2048 + mt*512

  const int* mrow = mask + b * Tn + s * 512 + l;
  unsigned long long bal64[8];
#pragma unroll
  for (int j = 0; j < 8; ++j) bal64[j] = __ballot(mrow[j * 64] != 0);

  ushort* Pw = &sm.P[w][0];
  uint32_t* Pw32 = reinterpret_cast<uint32_t*>(Pw);

  float m = -1e30f, lsum = 0.f;                    // lsum is PER-LANE partial
  floatx4 acc[4];
#pragma unroll
  for (int mt = 0; mt < 4; ++mt) acc[mt] = (floatx4){0.f, 0.f, 0.f, 0.f};

  short8 kf[2][4];
#pragma unroll
  for (int t = 0; t < 2; ++t)
#pragma unroll
    for (int h = 0; h < 2; ++h)
      kf[0][t * 2 + h] = *reinterpret_cast<const short8*>(kp + t * 1024 + h * 32);

#pragma unroll
  for (int it = 0; it < 16; ++it) {
    const int cur = it & 1, nxt = cur ^ 1;
    if (it < 15) {                                 // prefetch next K tile
#pragma unroll
      for (int t = 0; t < 2; ++t)
#pragma unroll
        for (int h = 0; h < 2; ++h)
          kf[nxt][t * 2 + h] =
              *reinterpret_cast<const short8*>(kp + (it + 1) * 2048 + t * 1024 + h * 32);
    }
    short8 vf[4];                                  // V tile: contiguous 4KB block
#pragma unroll
    for (int mt = 0; mt < 4; ++mt)
      vf[mt] = *reinterpret_cast<const short8*>(vp + it * 2048 + mt * 512);

    // ---- QK^T (S^T): lane holds q=lq (col), kv = t*16 + g*4 + r; q pre-scaled ----
    float sc[2][4];
#pragma unroll
    for (int t = 0; t < 2; ++t) {
      floatx4 z = (floatx4){0.f, 0.f, 0.f, 0.f};
      z = __builtin_amdgcn_mfma_f32_16x16x32_bf16(kf[cur][t * 2 + 0], qf0, z, 0, 0, 0);
      z = __builtin_amdgcn_mfma_f32_16x16x32_bf16(kf[cur][t * 2 + 1], qf1, z, 0, 0, 0);
#pragma unroll
      for (int r = 0; r < 4; ++r) sc[t][r] = z[r];
    }
    // ---- mask (skipped when tile fully unmasked — wave-uniform test) ----
    unsigned int bal32 = (unsigned int)(bal64[it >> 1] >> ((it & 1) * 32));
    if (bal32 != 0xFFFFFFFFu) {
#pragma unroll
      for (int t = 0; t < 2; ++t)
#pragma unroll
        for (int r = 0; r < 4; ++r)
          if (!((bal32 >> (t * 16 + g * 4 + r)) & 1u)) sc[t][r] = -1e9f;
    }
    // ---- per-lane max; rescale only when it grows past m+8 (no shuffles) ----
    float pmax = fmaxf(fmaxf(fmaxf(sc[0][0], sc[0][1]), fmaxf(sc[0][2], sc[0][3])),
                       fmaxf(fmaxf(sc[1][0], sc[1][1]), fmaxf(sc[1][2], sc[1][3])));
    if (!__all(pmax - m <= 8.0f)) {
      float rm = fmaxf(pmax, __shfl_xor(pmax, 16));
      rm = fmaxf(rm, __shfl_xor(rm, 32));
      float mnew = fmaxf(m, rm);
      float alpha = __builtin_amdgcn_exp2f((m - mnew) * kLog2e);
      lsum *= alpha;
#pragma unroll
      for (int mt = 0; mt < 4; ++mt) acc[mt] *= alpha;
      m = mnew;
    }
    // ---- p = exp2(sc*k - m*k): 1 fma + 1 exp each ----
    float nmk = m * kLog2e;
    float p[8];
#pragma unroll
    for (int t = 0; t < 2; ++t)
#pragma unroll
      for (int r = 0; r < 4; ++r)
        p[t * 4 + r] = __builtin_amdgcn_exp2f(__builtin_fmaf(sc[t][r], kLog2e, -nmk));
    lsum += ((p[0] + p[1]) + (p[2] + p[3])) + ((p[4] + p[5]) + (p[6] + p[7]));
    // ---- pack to bf16, P round-trip through LDS (within-wave dep only) ----
    uint2v pw0, pw1;
    pw0[0] = cvt_pk(p[0], p[1]); pw0[1] = cvt_pk(p[2], p[3]);
    pw1[0] = cvt_pk(p[4], p[5]); pw1[1] = cvt_pk(p[6], p[7]);
    *reinterpret_cast<uint2v*>(Pw32 + lq * 20 + g * 2) = pw0;
    *reinterpret_cast<uint2v*>(Pw32 + lq * 20 + 8 + g * 2) = pw1;
    short8 pf = *reinterpret_cast<const short8*>(Pw + lq * 40 + g * 8);
    // ---- PV: out^T += V^T @ P^T ----
#pragma unroll
    for (int mt = 0; mt < 4; ++mt)
      acc[mt] = __builtin_amdgcn_mfma_f32_16x16x32_bf16(vf[mt], pf, acc[mt], 0, 0, 0);
  }

  // finalize per-row lsum (reduce per-lane partials over the 4 g-lanes)
  lsum += __shfl_xor(lsum, 16);
  lsum += __shfl_xor(lsum, 32);

  __syncthreads();                                 // P dead; safe to overwrite (union)
  if (s > 0) {
#pragma unroll
    for (int mt = 0; mt < 4; ++mt)
      *reinterpret_cast<floatx4*>(&sm.mg.accS[qt][s - 1][l][mt * 4]) = acc[mt];
    sm.mg.mS[qt][s - 1][l] = m;
    sm.mg.lS[qt][s - 1][l] = lsum;
  }
  __syncthreads();
  if (s == 0) {
    float mtot = m;
#pragma unroll
    for (int si = 0; si < 3; ++si) mtot = fmaxf(mtot, sm.mg.mS[qt][si][l]);
    float e0 = __builtin_amdgcn_exp2f((m - mtot) * kLog2e);
    float ltot = lsum * e0;
    float res[4][4];
#pragma unroll
    for (int mt = 0; mt < 4; ++mt)
#pragma unroll
      for (int r = 0; r < 4; ++r) res[mt][r] = acc[mt][r] * e0;
#pragma unroll
    for (int si = 0; si < 3; ++si) {
      float e = __builtin_amdgcn_exp2f((sm.mg.mS[qt][si][l] - mtot) * kLog2e);
      ltot += sm.mg.lS[qt][si][l] * e;
#pragma unroll
      for (int mt = 0; mt < 4; ++mt) {
        floatx4 a = *reinterpret_cast<const floatx4*>(&sm.mg.accS[qt][si][l][mt * 4]);
#pragma unroll
        for (int r = 0; r < 4; ++r) res[mt][r] += a[r] * e;
      }
    }
    float inv = 1.0f / ltot;
    float* obase = out + ((size_t)(b * Tn + q0 + lq)) * Hn;
#pragma unroll
    for (int mt = 0; mt < 4; ++mt) {
      floatx4 o;
#pragma unroll
      for (int r = 0; r < 4; ++r) o[r] = res[mt][r] * inv;
      *reinterpret_cast<floatx4*>(obase + mt * 16 + g * 4) = o;
    }
  }
}

// ---------------------------------------------------------------------------
extern "C" void kernel_launch(void* const* d_in, const int* in_sizes, int n_in,
                              void* d_out, int out_size, void* d_ws, size_t ws_size,
                              hipStream_t stream) {
  const float* x  = (const float*)d_in[0];
  const float* Wq = (const float*)d_in[1];
  const float* bq = (const float*)d_in[2];
  const float* Wk = (const float*)d_in[3];
  const float* bk = (const float*)d_in[4];
  const float* Wv = (const float*)d_in[5];
  const float* bv = (const float*)d_in[6];
  const int* mask = (const int*)d_in[7];
  float* outp = (float*)d_out;

  ushort* wpack = (ushort*)d_ws;                       // 384 KB
  ushort* qbuf  = wpack + 196608;                      // 2 MB bf16 (pre-scaled by 1/8)
  ushort* kbuf  = qbuf + (size_t)16384 * 64;           // 2 MB
  ushort* vT2   = kbuf + (size_t)16384 * 64;           // [8][64][64][32] bf16, 2 MB

  hipLaunchKernelGGL(k_packw, dim3(384), dim3(64), 0, stream, Wq, Wk, Wv, wpack);
  hipLaunchKernelGGL(k_qkv, dim3(1024), dim3(256), 0, stream, x, wpack, bq, bk, bv,
                     qbuf, kbuf, vT2);
  hipLaunchKernelGGL(k_attn, dim3(512), dim3(512), 0, stream, qbuf, kbuf, vT2, mask, outp);
}